// Round 8
// baseline (137.501 us; speedup 1.0000x reference)
//
#include <hip/hip_runtime.h>

typedef _Float16 f16;
typedef __attribute__((ext_vector_type(8))) _Float16 f16x8;
typedef __attribute__((ext_vector_type(4))) float f32x4;
typedef __attribute__((ext_vector_type(4))) unsigned int u32x4;
typedef __attribute__((ext_vector_type(8))) unsigned short ushort8;

#define QF   64
#define GG   120
#define HID  128
#define NACT 20
#define BTOT 2048
#define UCH  4

// ---- workspace layout (bytes) ----
#define WEFF_OFF 0u           // 120 * 16KB f16 frag-order = 1,966,080
#define XH_OFF   1966080u     // 2048*64 f16 = 262,144
#define XL_OFF   2228224u
#define W1F_OFF  2490368u     // 32KB f16 frag-order (k-permuted)
#define MISC_OFF 2523136u     // bmean[128], wmean[128], cb
#define CAYL_OFF 2525184u     // 120*120 i32
#define FPT_OFF  2582784u     // 120*64 i32
#define S4_OFF   2613504u     // 24 i32 (pad)
#define CREP_OFF 2613632u     // 5 i32 (pad)
#define UBYC_OFF 2613760u     // 20*6 i32 (pad)
#define ABUF_OFF 2614272u     // 120*64*128 f32 = 3,932,160
#define M_OFF    ABUF_OFF     // m[120][2048] aliases ABUF (dead by mlp)

template <typename T>
__device__ __forceinline__ void keepv(T& v) { asm volatile("" : "+v"(v)); }

__device__ __forceinline__ void idx_to_perm(int i, int p[5]) {
    int avail[5] = {0, 1, 2, 3, 4};
    const int f[4] = {24, 6, 2, 1};
    for (int k = 0; k < 4; ++k) {
        int d = i / f[k]; i %= f[k];
        p[k] = avail[d];
        for (int j = d; j < 4 - k; ++j) avail[j] = avail[j + 1];
    }
    p[4] = avail[0];
}

__device__ __forceinline__ int perm_to_idx(const int p[5]) {
    const int f[4] = {24, 6, 2, 1};
    int idx = 0;
    for (int k = 0; k < 4; ++k) {
        int c = 0;
        for (int j = k + 1; j < 5; ++j) c += (p[j] < p[k]) ? 1 : 0;
        idx += c * f[k];
    }
    return idx;
}

__device__ __forceinline__ unsigned short f2h(float f) {
    f16 h = (f16)f;
    return __builtin_bit_cast(unsigned short, h);
}
__device__ __forceinline__ float h2f(unsigned short u) {
    return (float)__builtin_bit_cast(f16, u);
}

// One fully-parallel prep kernel: tables + input splits + misc.
__global__ void prep(const float* __restrict__ x, const float* __restrict__ W1,
                     const float* __restrict__ eq_bias, const float* __restrict__ Wout,
                     const float* __restrict__ bout,
                     int* __restrict__ cayley, int* __restrict__ fpt,
                     int* __restrict__ s4list, int* __restrict__ crep,
                     int* __restrict__ ubyc, float* __restrict__ misc,
                     unsigned short* __restrict__ xh, unsigned short* __restrict__ xl,
                     unsigned short* __restrict__ w1f) {
    int b = blockIdx.x, t = threadIdx.x;
    if (b < 57) {                         // cayley[a][c] = idx(perm_a o perm_c)
        int idx = b * 256 + t;
        if (idx < GG * GG) {
            int a = idx / GG, c = idx % GG;
            int pa[5], pb[5], pc[5];
            idx_to_perm(a, pa); idx_to_perm(c, pb);
            for (int k = 0; k < 5; ++k) pc[k] = pa[pb[k]];
            cayley[idx] = perm_to_idx(pc);
        }
    } else if (b < 87) {                  // fpt[v][r] (featperm)
        int idx = (b - 57) * 256 + t;     // < 7680
        int v = idx >> 6, r = idx & 63;
        int pv[5], pi[5];
        idx_to_perm(v, pv);
        for (int k = 0; k < 5; ++k) pi[pv[k]] = k;   // inverse
        int val = r & 32;
        for (int k = 0; k < 5; ++k)
            val |= ((r >> (4 - pi[k])) & 1) << (4 - k);
        fpt[idx] = val;
    } else if (b < 95) {                  // W1 -> f16 B-frags, k-PERMUTED order
        int idx = (b - 87) * 256 + t;     // < 2048
        int fg = idx >> 6, lane = idx & 63;
        int nt = fg >> 2, ks = fg & 3;
        int n = nt * 16 + (lane & 15), kg = lane >> 4;
        ushort8 v;
#pragma unroll
        for (int j = 0; j < 8; ++j) {
            // h(ks,kg,j) = ks*32 + (j>>2)*16 + kg*4 + (j&3)  -- matches E-frag layout
            int h = ks * 32 + ((j >> 2) << 4) + (kg << 2) + (j & 3);
            v[j] = f2h(W1[h * HID + n]);
        }
        *(ushort8*)(w1f + idx * 8) = v;
    } else if (b < 607) {                 // split x -> f16 hi/lo
        int idx = (b - 95) * 256 + t;     // < 131072
        float f = x[idx];
        unsigned short h = f2h(f);
        xh[idx] = h;
        xl[idx] = f2h(f - h2f(h));
    } else if (b == 607) {                // misc
        if (t < HID) {
            float s = 0.f;
            for (int g = 0; g < GG; ++g) s += eq_bias[g * HID + t];
            misc[t] = s * (1.f / GG);
            float wv = 0.f;
            for (int n = 0; n < NACT; ++n) wv += Wout[t * NACT + n];
            misc[HID + t] = wv * (1.f / NACT);
            if (t == 0) {
                float c = 0.f;
                for (int n = 0; n < NACT; ++n) c += bout[n];
                misc[2 * HID] = c * (1.f / NACT);
            }
        }
    } else {                              // group tables
        if (t < 24) {
            int i = t, avail[4] = {0, 1, 2, 3}, p[5];
            const int f3[3] = {6, 2, 1};
            for (int k = 0; k < 3; ++k) {
                int d = i / f3[k]; i %= f3[k];
                p[k] = avail[d];
                for (int j = d; j < 3 - k; ++j) avail[j] = avail[j + 1];
            }
            p[3] = avail[0]; p[4] = 4;
            s4list[t] = perm_to_idx(p);
        }
        if (t < 5) {
            int c[5] = {0, 1, 2, 3, 4};
            c[t] = 4; c[4] = t;
            crep[t] = perm_to_idx(c);
        }
        if (t < NACT) {
            int cnt = 0;
            for (int p = 0; p < GG; ++p) {
                int pp[5]; idx_to_perm(p, pp);
                int a = pp[0] * 4 + (pp[1] > pp[0] ? pp[1] - 1 : pp[1]);
                if (a == t) ubyc[t * 6 + cnt++] = p;
            }
        }
    }
}

// Stage 1: A[y][r][h] = sum_{s in S4} eqw[cayley[s][y]][fpt[s][r]][h]
__global__ void weff_stage1(const float* __restrict__ eqw,
                            const int* __restrict__ cayley,
                            const int* __restrict__ fpt,
                            const int* __restrict__ s4list,
                            float* __restrict__ Abuf) {
    __shared__ int sg[24];
    __shared__ int sfp[24][64];
    int y = blockIdx.x, t = threadIdx.x;
    if (t < 24) sg[t] = cayley[s4list[t] * GG + y];
    for (int i = t; i < 24 * 64; i += 256)
        sfp[i >> 6][i & 63] = fpt[s4list[i >> 6] * QF + (i & 63)];
    __syncthreads();
    int h = blockIdx.y * 32 + (t & 31), rg = t >> 5;
    float acc[8];
#pragma unroll
    for (int rr = 0; rr < 8; ++rr) acc[rr] = 0.f;
    for (int si = 0; si < 24; ++si) {
        const float* src = eqw + (unsigned)sg[si] * QF * HID + h;
#pragma unroll
        for (int rr = 0; rr < 8; ++rr)
            acc[rr] += src[sfp[si][rg * 8 + rr] * HID];
    }
    float* dst = Abuf + (unsigned)(y * QF + rg * 8) * HID + h;
#pragma unroll
    for (int rr = 0; rr < 8; ++rr) dst[rr * HID] = acc[rr];
}

// Stage 2: Weff[u][q][h] = (1/G) sum_i A[cay[ci][u]][fpt[ci][q]][h]; emit f16 A-frags
// frag order per u: [hm(8)][ks(2)][lane(64)] x ushort8, value = Weff[q][h],
// q = ks*32 + (lane>>4)*8 + j, h = hm*16 + (lane&15)
__global__ void weff_stage2(const float* __restrict__ Abuf,
                            const int* __restrict__ cayley,
                            const int* __restrict__ fpt,
                            const int* __restrict__ crep,
                            unsigned short* __restrict__ weff) {
    __shared__ float Wacc[HID][QF + 1];   // [h][q], stride 65
    __shared__ int yv[5];
    __shared__ int rp[5][64];
    int u = blockIdx.x, t = threadIdx.x;
    if (t < 5) yv[t] = cayley[crep[t] * GG + u];
    for (int i = t; i < 5 * 64; i += 256)
        rp[i >> 6][i & 63] = fpt[crep[i >> 6] * QF + (i & 63)];
    __syncthreads();
    int h = t & 127, qg = t >> 7;
    for (int i = 0; i < 32; ++i) {
        int q = qg * 32 + i;
        float s = 0.f;
#pragma unroll
        for (int j = 0; j < 5; ++j)
            s += Abuf[(unsigned)(yv[j] * QF + rp[j][q]) * HID + h];
        Wacc[h][q] = s * (1.f / GG);
    }
    __syncthreads();
    for (int e = t; e < 1024; e += 256) {
        int fg = e >> 6, lane = e & 63;
        int hm = fg >> 1, ks = fg & 1;
        int hh = hm * 16 + (lane & 15), q0 = ks * 32 + (lane >> 4) * 8;
        ushort8 v;
#pragma unroll
        for (int j = 0; j < 8; ++j) v[j] = f2h(Wacc[hh][q0 + j]);
        *(ushort8*)(weff + (unsigned)(u * 16 + fg) * 64 * 8 + lane * 8) = v;
    }
}

__device__ __forceinline__ f32x4 mfma16(f16x8 a, f16x8 b, f32x4 c) {
    return __builtin_amdgcn_mfma_f32_16x16x32_f16(a, b, c, 0, 0, 0);
}

// Fused MLP: 240 blocks x 512 thr; 8 waves x 32 rows; W1 + Weff(dbuf) in LDS (64KB);
// swapped stage-A (E^T in regs); stage-B A-frags are lane-local (k-permuted W1).
__global__ __launch_bounds__(512, 1)
void mlp_mfma(const unsigned short* __restrict__ xh,
              const unsigned short* __restrict__ xl,
              const unsigned short* __restrict__ weff,
              const unsigned short* __restrict__ w1f,
              const float* __restrict__ b1,
              const float* __restrict__ misc,
              float* __restrict__ m) {
    __shared__ __align__(16) unsigned short w1s[16384];      // 32KB
    __shared__ __align__(16) unsigned short wefs[2][8192];   // 2x16KB

    int bid = blockIdx.x;
    int rowtile = bid & 7;            // 8 row tiles of 256
    int uc = bid >> 3;                // 30 u-chunks
    int u0 = uc * UCH;
    int rowbase = rowtile * 256;
    int t = threadIdx.x;
    int w = t >> 6, lane = t & 63;
    int lm = lane & 15, kg = lane >> 4;
    int xbase = rowbase + w * 32;

    // stage W1 + Weff[u0] into LDS
#pragma unroll
    for (int i = 0; i < 4; ++i)
        *(u32x4*)(w1s + (i * 512 + t) * 8) = *(const u32x4*)(w1f + (i * 512 + t) * 8);
#pragma unroll
    for (int i = 0; i < 2; ++i)
        *(u32x4*)(wefs[0] + (i * 512 + t) * 8) =
            *(const u32x4*)(weff + (unsigned)u0 * 8192 + (i * 512 + t) * 8);

    // pin X frags (B-operand of swapped stage A): [xt][ks][hi/lo]
    f16x8 xb[2][2][2];
#pragma unroll
    for (int xt = 0; xt < 2; ++xt)
#pragma unroll
        for (int ks = 0; ks < 2; ++ks) {
            int off = (xbase + xt * 16 + lm) * QF + ks * 32 + kg * 8;
            xb[xt][ks][0] = *(const f16x8*)(xh + off);
            xb[xt][ks][1] = *(const f16x8*)(xl + off);
            keepv(xb[xt][ks][0]); keepv(xb[xt][ks][1]);
        }
    // pin b1 / wmean per lane (n = nt*16+lm)
    float b1v[8], wmv[8];
#pragma unroll
    for (int nt = 0; nt < 8; ++nt) {
        b1v[nt] = b1[nt * 16 + lm];
        wmv[nt] = misc[HID + nt * 16 + lm];
        keepv(b1v[nt]); keepv(wmv[nt]);
    }
    __syncthreads();

    int cur = 0;

#pragma unroll 1
    for (int ui = 0; ui < UCH; ++ui) {
        int u = u0 + ui;
        bool hasNext = (ui + 1 < UCH);
        // prefetch next-u Weff into regs (write to LDS after compute)
        u32x4 pf0, pf1;
        if (hasNext) {
            const unsigned short* ws = weff + (unsigned)(u + 1) * 8192;
            pf0 = *(const u32x4*)(ws + t * 8);
            pf1 = *(const u32x4*)(ws + (512 + t) * 8);
        }

        // ---- stage A (swapped): acc[xt][hm] = E^T tile ----
        // lane holds E for x-row = xbase+xt*16+lm, h = hm*16 + kg*4 + r
        f32x4 acc[2][8];
#pragma unroll
        for (int xt = 0; xt < 2; ++xt)
#pragma unroll
            for (int hm = 0; hm < 8; ++hm) acc[xt][hm] = (f32x4){0.f, 0.f, 0.f, 0.f};
        const unsigned short* wb = wefs[cur];
#pragma unroll
        for (int hm = 0; hm < 8; ++hm)
#pragma unroll
            for (int ks = 0; ks < 2; ++ks) {
                f16x8 wf = *(const f16x8*)(wb + ((hm * 2 + ks) * 64 + lane) * 8);
#pragma unroll
                for (int xt = 0; xt < 2; ++xt) {
                    acc[xt][hm] = mfma16(wf, xb[xt][ks][0], acc[xt][hm]);
                    acc[xt][hm] = mfma16(wf, xb[xt][ks][1], acc[xt][hm]);
                }
            }

        // ---- epilogue A: +bmean, relu, f16 split, pack ----
        // PH0[hm] = f16(e[r0]),f16(e[r1]);  PH1[hm] = r2,r3;  PL* = residuals
        unsigned PH0[2][8], PH1[2][8], PL0[2][8], PL1[2][8];
#pragma unroll
        for (int hm = 0; hm < 8; ++hm) {
            f32x4 bmv = *(const f32x4*)(misc + hm * 16 + kg * 4);
#pragma unroll
            for (int xt = 0; xt < 2; ++xt) {
                float e0 = acc[xt][hm][0] + bmv[0]; e0 = e0 > 0.f ? e0 : 0.f;
                float e1 = acc[xt][hm][1] + bmv[1]; e1 = e1 > 0.f ? e1 : 0.f;
                float e2 = acc[xt][hm][2] + bmv[2]; e2 = e2 > 0.f ? e2 : 0.f;
                float e3 = acc[xt][hm][3] + bmv[3]; e3 = e3 > 0.f ? e3 : 0.f;
                auto h0 = __builtin_amdgcn_cvt_pkrtz(e0, e1);
                auto h1 = __builtin_amdgcn_cvt_pkrtz(e2, e3);
                auto l0 = __builtin_amdgcn_cvt_pkrtz(e0 - (float)h0[0], e1 - (float)h0[1]);
                auto l1 = __builtin_amdgcn_cvt_pkrtz(e2 - (float)h1[0], e3 - (float)h1[1]);
                PH0[xt][hm] = __builtin_bit_cast(unsigned, h0);
                PH1[xt][hm] = __builtin_bit_cast(unsigned, h1);
                PL0[xt][hm] = __builtin_bit_cast(unsigned, l0);
                PL1[xt][hm] = __builtin_bit_cast(unsigned, l1);
            }
        }

        // ---- stage B: A-frags are lane-local (W1 was stored k-permuted) ----
        // MFMA ks uses h(ks,kg,j) = ks*32 + (j>>2)*16 + kg*4 + (j&3):
        //   A-frag = [PH0[2ks], PH1[2ks], PH0[2ks+1], PH1[2ks+1]]
        f32x4 acc2[2][8];
#pragma unroll
        for (int xt = 0; xt < 2; ++xt)
#pragma unroll
            for (int nt = 0; nt < 8; ++nt) acc2[xt][nt] = (f32x4){0.f, 0.f, 0.f, 0.f};
#pragma unroll
        for (int ks = 0; ks < 4; ++ks) {
            f16x8 paH[2], paL[2];
#pragma unroll
            for (int xt = 0; xt < 2; ++xt) {
                u32x4 ph = {PH0[xt][2 * ks], PH1[xt][2 * ks],
                            PH0[xt][2 * ks + 1], PH1[xt][2 * ks + 1]};
                u32x4 pl = {PL0[xt][2 * ks], PL1[xt][2 * ks],
                            PL0[xt][2 * ks + 1], PL1[xt][2 * ks + 1]};
                paH[xt] = __builtin_bit_cast(f16x8, ph);
                paL[xt] = __builtin_bit_cast(f16x8, pl);
            }
#pragma unroll
            for (int nt = 0; nt < 8; ++nt) {
                f16x8 wf = *(const f16x8*)(w1s + ((nt * 4 + ks) * 64 + lane) * 8);
#pragma unroll
                for (int xt = 0; xt < 2; ++xt) {
                    acc2[xt][nt] = mfma16(paH[xt], wf, acc2[xt][nt]);
                    acc2[xt][nt] = mfma16(paL[xt], wf, acc2[xt][nt]);
                }
            }
        }

        // ---- epilogue B: relu(h2+b1).wmean, 16-lane reduce, store ----
        float ms[2][4];
#pragma unroll
        for (int xt = 0; xt < 2; ++xt)
#pragma unroll
            for (int r = 0; r < 4; ++r) ms[xt][r] = 0.f;
#pragma unroll
        for (int nt = 0; nt < 8; ++nt)
#pragma unroll
            for (int xt = 0; xt < 2; ++xt)
#pragma unroll
                for (int r = 0; r < 4; ++r) {
                    float v = acc2[xt][nt][r] + b1v[nt];
                    v = v > 0.f ? v : 0.f;
                    ms[xt][r] += v * wmv[nt];
                }
#pragma unroll
        for (int off = 1; off < 16; off <<= 1)
#pragma unroll
            for (int xt = 0; xt < 2; ++xt)
#pragma unroll
                for (int r = 0; r < 4; ++r)
                    ms[xt][r] += __shfl_xor(ms[xt][r], off, 64);
        if (lm == 0) {
#pragma unroll
            for (int xt = 0; xt < 2; ++xt) {
                f32x4 o = {ms[xt][0], ms[xt][1], ms[xt][2], ms[xt][3]};
                *(f32x4*)(m + (unsigned)u * BTOT + xbase + xt * 16 + kg * 4) = o;
            }
        }

        // ---- write prefetched Weff into other buffer, single barrier ----
        if (hasNext) {
            *(u32x4*)(wefs[cur ^ 1] + t * 8) = pf0;
            *(u32x4*)(wefs[cur ^ 1] + (512 + t) * 8) = pf1;
            __syncthreads();
            cur ^= 1;
        }
    }
}

__global__ void reduce_out(const float* __restrict__ m,
                           const int* __restrict__ ubyc,
                           const float* __restrict__ misc,
                           float* __restrict__ out) {
    int idx = blockIdx.x * 256 + threadIdx.x;   // bt*20 + a
    if (idx >= BTOT * NACT) return;
    int bt = idx / NACT, a = idx % NACT;
    float s = 0.f;
#pragma unroll
    for (int j = 0; j < 6; ++j) s += m[ubyc[a * 6 + j] * BTOT + bt];
    out[idx] = s * (1.f / 6.f) + misc[2 * HID];
}

extern "C" void kernel_launch(void* const* d_in, const int* in_sizes, int n_in,
                              void* d_out, int out_size, void* d_ws, size_t ws_size,
                              hipStream_t stream) {
    const float* x       = (const float*)d_in[0];
    const float* eqw     = (const float*)d_in[1];
    const float* eq_bias = (const float*)d_in[2];
    const float* W1      = (const float*)d_in[3];
    const float* b1      = (const float*)d_in[4];
    const float* Wout    = (const float*)d_in[5];
    const float* bout    = (const float*)d_in[6];
    float* out           = (float*)d_out;

    char* ws = (char*)d_ws;
    unsigned short* weff = (unsigned short*)(ws + WEFF_OFF);
    unsigned short* xhb  = (unsigned short*)(ws + XH_OFF);
    unsigned short* xlb  = (unsigned short*)(ws + XL_OFF);
    unsigned short* w1f  = (unsigned short*)(ws + W1F_OFF);
    float* misc   = (float*)(ws + MISC_OFF);
    int* cayley   = (int*)(ws + CAYL_OFF);
    int* fpt      = (int*)(ws + FPT_OFF);
    int* s4list   = (int*)(ws + S4_OFF);
    int* crep     = (int*)(ws + CREP_OFF);
    int* ubyc     = (int*)(ws + UBYC_OFF);
    float* Abuf   = (float*)(ws + ABUF_OFF);
    float* mbuf   = (float*)(ws + M_OFF);   // aliases Abuf (dead by mlp)

    hipLaunchKernelGGL(prep, dim3(609), dim3(256), 0, stream,
                       x, W1, eq_bias, Wout, bout,
                       cayley, fpt, s4list, crep, ubyc, misc, xhb, xlb, w1f);
    hipLaunchKernelGGL(weff_stage1, dim3(120, 4), dim3(256), 0, stream,
                       eqw, cayley, fpt, s4list, Abuf);
    hipLaunchKernelGGL(weff_stage2, dim3(120), dim3(256), 0, stream,
                       Abuf, cayley, fpt, crep, weff);
    hipLaunchKernelGGL(mlp_mfma, dim3(240), dim3(512), 0, stream,
                       xhb, xlb, weff, w1f, b1, misc, mbuf);
    hipLaunchKernelGGL(reduce_out, dim3((BTOT * NACT + 255) / 256), dim3(256), 0, stream,
                       mbuf, ubyc, misc, out);
}

// Round 9
// 94.047 us; speedup vs baseline: 1.4620x; 1.4620x over previous
//
#include <hip/hip_runtime.h>

typedef _Float16 f16;
typedef __attribute__((ext_vector_type(8))) _Float16 f16x8;
typedef __attribute__((ext_vector_type(4))) float f32x4;
typedef __attribute__((ext_vector_type(4))) unsigned int u32x4;
typedef __attribute__((ext_vector_type(8))) unsigned short ushort8;

#define QF   64
#define GG   120
#define HID  128
#define NACT 20
#define BTOT 2048
#define UCH  4

// ---- workspace layout (bytes) ----
#define WEFF_OFF 0u           // 120 * 16KB f16 frag-order = 1,966,080
#define XH_OFF   1966080u     // 2048*64 f16 = 262,144
#define XL_OFF   2228224u
#define W1F_OFF  2490368u     // 32KB f16 frag-order (k-permuted)
#define MISC_OFF 2523136u     // bmean[128], wmean[128], cb
#define CAYL_OFF 2525184u     // 120*120 i32
#define FPT_OFF  2582784u     // 120*64 i32
#define S4_OFF   2613504u     // 24 i32 (pad)
#define CREP_OFF 2613632u     // 5 i32 (pad)
#define UBYC_OFF 2613760u     // 20*6 i32 (pad)
#define ABUF_OFF 2614272u     // 120*64*128 f32 = 3,932,160
#define M_OFF    ABUF_OFF     // m[120][2048] aliases ABUF (dead by mlp)

template <typename T>
__device__ __forceinline__ void keepv(T& v) { asm volatile("" : "+v"(v)); }

// ---- packed-nibble permutation helpers (register-only, no scratch) ----
// perm p stored as unsigned: nibble k (bits 4k..4k+3) = p[k], k=0..4
__device__ __forceinline__ unsigned idx_to_packed(int i) {
    unsigned avail = 0x43210u, pp = 0u;
    const int fct[4] = {24, 6, 2, 1};
#pragma unroll
    for (int k = 0; k < 4; ++k) {
        int d = i / fct[k]; i -= d * fct[k];
        pp |= ((avail >> (4 * d)) & 0xFu) << (4 * k);
        unsigned mask = (1u << (4 * d)) - 1u;
        avail = (avail & mask) | ((avail >> 4) & ~mask);
    }
    pp |= (avail & 0xFu) << 16;
    return pp;
}

__device__ __forceinline__ int packed_to_idx(unsigned pp) {
    const int fct[4] = {24, 6, 2, 1};
    int idx = 0;
#pragma unroll
    for (int k = 0; k < 4; ++k) {
        unsigned pk = (pp >> (4 * k)) & 0xFu;
        int c = 0;
#pragma unroll
        for (int j = k + 1; j < 5; ++j)
            c += (int)(((pp >> (4 * j)) & 0xFu) < pk);
        idx += c * fct[k];
    }
    return idx;
}

__device__ __forceinline__ unsigned compose_packed(unsigned pa, unsigned pb) {
    unsigned pc = 0;
#pragma unroll
    for (int k = 0; k < 5; ++k) {
        unsigned bk = (pb >> (4 * k)) & 0xFu;
        pc |= ((pa >> (4 * bk)) & 0xFu) << (4 * k);
    }
    return pc;
}

__device__ __forceinline__ unsigned invert_packed(unsigned pp) {
    unsigned pi = 0;
#pragma unroll
    for (int k = 0; k < 5; ++k)
        pi |= (unsigned)k << (4 * ((pp >> (4 * k)) & 0xFu));
    return pi;
}

__device__ __forceinline__ unsigned short f2h(float f) {
    f16 h = (f16)f;
    return __builtin_bit_cast(unsigned short, h);
}
__device__ __forceinline__ float h2f(unsigned short u) {
    return (float)__builtin_bit_cast(f16, u);
}

// One fully-parallel prep kernel: tables + input splits + misc.
__global__ void prep(const float* __restrict__ x, const float* __restrict__ W1,
                     const float* __restrict__ eq_bias, const float* __restrict__ Wout,
                     const float* __restrict__ bout,
                     int* __restrict__ cayley, int* __restrict__ fpt,
                     int* __restrict__ s4list, int* __restrict__ crep,
                     int* __restrict__ ubyc, float* __restrict__ misc,
                     unsigned short* __restrict__ xh, unsigned short* __restrict__ xl,
                     unsigned short* __restrict__ w1f) {
    int b = blockIdx.x, t = threadIdx.x;
    if (b < 57) {                         // cayley[a][c] = idx(perm_a o perm_c)
        int idx = b * 256 + t;
        if (idx < GG * GG) {
            int a = idx / GG, c = idx % GG;
            unsigned pa = idx_to_packed(a), pc = idx_to_packed(c);
            cayley[idx] = packed_to_idx(compose_packed(pa, pc));
        }
    } else if (b < 87) {                  // fpt[v][r] (featperm)
        int idx = (b - 57) * 256 + t;     // < 7680
        int v = idx >> 6, r = idx & 63;
        unsigned ppi = invert_packed(idx_to_packed(v));
        int val = r & 32;
#pragma unroll
        for (int k = 0; k < 5; ++k) {
            int pik = (ppi >> (4 * k)) & 0xF;
            val |= ((r >> (4 - pik)) & 1) << (4 - k);
        }
        fpt[idx] = val;
    } else if (b < 95) {                  // W1 -> f16 B-frags, k-PERMUTED order
        int idx = (b - 87) * 256 + t;     // < 2048
        int fg = idx >> 6, lane = idx & 63;
        int nt = fg >> 2, ks = fg & 3;
        int n = nt * 16 + (lane & 15), kg = lane >> 4;
        ushort8 v;
#pragma unroll
        for (int j = 0; j < 8; ++j) {
            // h(ks,kg,j) = ks*32 + (j>>2)*16 + kg*4 + (j&3)  -- matches E-frag layout
            int h = ks * 32 + ((j >> 2) << 4) + (kg << 2) + (j & 3);
            v[j] = f2h(W1[h * HID + n]);
        }
        *(ushort8*)(w1f + idx * 8) = v;
    } else if (b < 607) {                 // split x -> f16 hi/lo
        int idx = (b - 95) * 256 + t;     // < 131072
        float f = x[idx];
        unsigned short h = f2h(f);
        xh[idx] = h;
        xl[idx] = f2h(f - h2f(h));
    } else if (b == 607) {                // misc
        if (t < HID) {
            float s = 0.f;
            for (int g = 0; g < GG; ++g) s += eq_bias[g * HID + t];
            misc[t] = s * (1.f / GG);
            float wv = 0.f;
            for (int n = 0; n < NACT; ++n) wv += Wout[t * NACT + n];
            misc[HID + t] = wv * (1.f / NACT);
            if (t == 0) {
                float c = 0.f;
                for (int n = 0; n < NACT; ++n) c += bout[n];
                misc[2 * HID] = c * (1.f / NACT);
            }
        }
    } else {                              // group tables (all register-only now)
        if (t < 24) {                     // S4 (perms fixing slot 4)
            unsigned avail = 0x3210u, pp = 0u;
            const int f3[3] = {6, 2, 1};
            int i = t;
#pragma unroll
            for (int k = 0; k < 3; ++k) {
                int d = i / f3[k]; i -= d * f3[k];
                pp |= ((avail >> (4 * d)) & 0xFu) << (4 * k);
                unsigned mask = (1u << (4 * d)) - 1u;
                avail = (avail & mask) | ((avail >> 4) & ~mask);
            }
            pp |= (avail & 0xFu) << 12;
            pp |= 4u << 16;
            s4list[t] = packed_to_idx(pp);
        }
        if (t < 5) {                      // transposition (t 4); t=4 -> identity
            unsigned pp = 0x43210u;
            pp &= ~(0xFu << (4 * t));
            pp &= ~(0xFu << 16);
            pp |= 4u << (4 * t);
            pp |= (unsigned)t << 16;
            crep[t] = packed_to_idx(pp);
        }
        if (t < NACT) {                   // coset membership lists
            int cnt = 0;
            for (int p = 0; p < GG; ++p) {
                unsigned pp = idx_to_packed(p);
                int p0 = pp & 0xF, p1 = (pp >> 4) & 0xF;
                int a = p0 * 4 + (p1 > p0 ? p1 - 1 : p1);
                if (a == t) ubyc[t * 6 + cnt++] = p;
            }
        }
    }
}

// Stage 1: A[y][r][h] = sum_{s in S4} eqw[cayley[s][y]][fpt[s][r]][h]
__global__ void weff_stage1(const float* __restrict__ eqw,
                            const int* __restrict__ cayley,
                            const int* __restrict__ fpt,
                            const int* __restrict__ s4list,
                            float* __restrict__ Abuf) {
    __shared__ int sg[24];
    __shared__ int sfp[24][64];
    int y = blockIdx.x, t = threadIdx.x;
    if (t < 24) sg[t] = cayley[s4list[t] * GG + y];
    for (int i = t; i < 24 * 64; i += 256)
        sfp[i >> 6][i & 63] = fpt[s4list[i >> 6] * QF + (i & 63)];
    __syncthreads();
    int h = blockIdx.y * 32 + (t & 31), rg = t >> 5;
    float acc[8];
#pragma unroll
    for (int rr = 0; rr < 8; ++rr) acc[rr] = 0.f;
    for (int si = 0; si < 24; ++si) {
        const float* src = eqw + (unsigned)sg[si] * QF * HID + h;
#pragma unroll
        for (int rr = 0; rr < 8; ++rr)
            acc[rr] += src[sfp[si][rg * 8 + rr] * HID];
    }
    float* dst = Abuf + (unsigned)(y * QF + rg * 8) * HID + h;
#pragma unroll
    for (int rr = 0; rr < 8; ++rr) dst[rr * HID] = acc[rr];
}

// Stage 2: Weff[u][q][h] = (1/G) sum_i A[cay[ci][u]][fpt[ci][q]][h]; emit f16 A-frags
// frag order per u: [hm(8)][ks(2)][lane(64)] x ushort8, value = Weff[q][h],
// q = ks*32 + (lane>>4)*8 + j, h = hm*16 + (lane&15)
__global__ void weff_stage2(const float* __restrict__ Abuf,
                            const int* __restrict__ cayley,
                            const int* __restrict__ fpt,
                            const int* __restrict__ crep,
                            unsigned short* __restrict__ weff) {
    __shared__ float Wacc[HID][QF + 1];   // [h][q], stride 65
    __shared__ int yv[5];
    __shared__ int rp[5][64];
    int u = blockIdx.x, t = threadIdx.x;
    if (t < 5) yv[t] = cayley[crep[t] * GG + u];
    for (int i = t; i < 5 * 64; i += 256)
        rp[i >> 6][i & 63] = fpt[crep[i >> 6] * QF + (i & 63)];
    __syncthreads();
    int h = t & 127, qg = t >> 7;
    for (int i = 0; i < 32; ++i) {
        int q = qg * 32 + i;
        float s = 0.f;
#pragma unroll
        for (int j = 0; j < 5; ++j)
            s += Abuf[(unsigned)(yv[j] * QF + rp[j][q]) * HID + h];
        Wacc[h][q] = s * (1.f / GG);
    }
    __syncthreads();
    for (int e = t; e < 1024; e += 256) {
        int fg = e >> 6, lane = e & 63;
        int hm = fg >> 1, ks = fg & 1;
        int hh = hm * 16 + (lane & 15), q0 = ks * 32 + (lane >> 4) * 8;
        ushort8 v;
#pragma unroll
        for (int j = 0; j < 8; ++j) v[j] = f2h(Wacc[hh][q0 + j]);
        *(ushort8*)(weff + (unsigned)(u * 16 + fg) * 64 * 8 + lane * 8) = v;
    }
}

__device__ __forceinline__ f32x4 mfma16(f16x8 a, f16x8 b, f32x4 c) {
    return __builtin_amdgcn_mfma_f32_16x16x32_f16(a, b, c, 0, 0, 0);
}

// Fused MLP: 240 blocks x 512 thr; 8 waves x 32 rows; W1 + Weff(dbuf) in LDS (64KB);
// swapped stage-A (E^T in regs); stage-B A-frags are lane-local (k-permuted W1).
__global__ __launch_bounds__(512, 1)
void mlp_mfma(const unsigned short* __restrict__ xh,
              const unsigned short* __restrict__ xl,
              const unsigned short* __restrict__ weff,
              const unsigned short* __restrict__ w1f,
              const float* __restrict__ b1,
              const float* __restrict__ misc,
              float* __restrict__ m) {
    __shared__ __align__(16) unsigned short w1s[16384];      // 32KB
    __shared__ __align__(16) unsigned short wefs[2][8192];   // 2x16KB

    int bid = blockIdx.x;
    int rowtile = bid & 7;            // 8 row tiles of 256
    int uc = bid >> 3;                // 30 u-chunks
    int u0 = uc * UCH;
    int rowbase = rowtile * 256;
    int t = threadIdx.x;
    int w = t >> 6, lane = t & 63;
    int lm = lane & 15, kg = lane >> 4;
    int xbase = rowbase + w * 32;

    // stage W1 + Weff[u0] into LDS
#pragma unroll
    for (int i = 0; i < 4; ++i)
        *(u32x4*)(w1s + (i * 512 + t) * 8) = *(const u32x4*)(w1f + (i * 512 + t) * 8);
#pragma unroll
    for (int i = 0; i < 2; ++i)
        *(u32x4*)(wefs[0] + (i * 512 + t) * 8) =
            *(const u32x4*)(weff + (unsigned)u0 * 8192 + (i * 512 + t) * 8);

    // pin X frags (B-operand of swapped stage A): [xt][ks][hi/lo]
    f16x8 xb[2][2][2];
#pragma unroll
    for (int xt = 0; xt < 2; ++xt)
#pragma unroll
        for (int ks = 0; ks < 2; ++ks) {
            int off = (xbase + xt * 16 + lm) * QF + ks * 32 + kg * 8;
            xb[xt][ks][0] = *(const f16x8*)(xh + off);
            xb[xt][ks][1] = *(const f16x8*)(xl + off);
            keepv(xb[xt][ks][0]); keepv(xb[xt][ks][1]);
        }
    // pin b1 / wmean per lane (n = nt*16+lm)
    float b1v[8], wmv[8];
#pragma unroll
    for (int nt = 0; nt < 8; ++nt) {
        b1v[nt] = b1[nt * 16 + lm];
        wmv[nt] = misc[HID + nt * 16 + lm];
        keepv(b1v[nt]); keepv(wmv[nt]);
    }
    __syncthreads();

    int cur = 0;

#pragma unroll 1
    for (int ui = 0; ui < UCH; ++ui) {
        int u = u0 + ui;
        bool hasNext = (ui + 1 < UCH);
        // prefetch next-u Weff into regs (write to LDS after compute)
        u32x4 pf0, pf1;
        if (hasNext) {
            const unsigned short* ws = weff + (unsigned)(u + 1) * 8192;
            pf0 = *(const u32x4*)(ws + t * 8);
            pf1 = *(const u32x4*)(ws + (512 + t) * 8);
        }

        // ---- stage A (swapped): acc[xt][hm] = E^T tile ----
        // lane holds E for x-row = xbase+xt*16+lm, h = hm*16 + kg*4 + r
        f32x4 acc[2][8];
#pragma unroll
        for (int xt = 0; xt < 2; ++xt)
#pragma unroll
            for (int hm = 0; hm < 8; ++hm) acc[xt][hm] = (f32x4){0.f, 0.f, 0.f, 0.f};
        const unsigned short* wb = wefs[cur];
#pragma unroll
        for (int hm = 0; hm < 8; ++hm)
#pragma unroll
            for (int ks = 0; ks < 2; ++ks) {
                f16x8 wf = *(const f16x8*)(wb + ((hm * 2 + ks) * 64 + lane) * 8);
#pragma unroll
                for (int xt = 0; xt < 2; ++xt) {
                    acc[xt][hm] = mfma16(wf, xb[xt][ks][0], acc[xt][hm]);
                    acc[xt][hm] = mfma16(wf, xb[xt][ks][1], acc[xt][hm]);
                }
            }

        // ---- epilogue A: +bmean, relu, f16 split, pack ----
        // PH0[hm] = f16(e[r0]),f16(e[r1]);  PH1[hm] = r2,r3;  PL* = residuals
        unsigned PH0[2][8], PH1[2][8], PL0[2][8], PL1[2][8];
#pragma unroll
        for (int hm = 0; hm < 8; ++hm) {
            f32x4 bmv = *(const f32x4*)(misc + hm * 16 + kg * 4);
#pragma unroll
            for (int xt = 0; xt < 2; ++xt) {
                float e0 = acc[xt][hm][0] + bmv[0]; e0 = e0 > 0.f ? e0 : 0.f;
                float e1 = acc[xt][hm][1] + bmv[1]; e1 = e1 > 0.f ? e1 : 0.f;
                float e2 = acc[xt][hm][2] + bmv[2]; e2 = e2 > 0.f ? e2 : 0.f;
                float e3 = acc[xt][hm][3] + bmv[3]; e3 = e3 > 0.f ? e3 : 0.f;
                auto h0 = __builtin_amdgcn_cvt_pkrtz(e0, e1);
                auto h1 = __builtin_amdgcn_cvt_pkrtz(e2, e3);
                auto l0 = __builtin_amdgcn_cvt_pkrtz(e0 - (float)h0[0], e1 - (float)h0[1]);
                auto l1 = __builtin_amdgcn_cvt_pkrtz(e2 - (float)h1[0], e3 - (float)h1[1]);
                PH0[xt][hm] = __builtin_bit_cast(unsigned, h0);
                PH1[xt][hm] = __builtin_bit_cast(unsigned, h1);
                PL0[xt][hm] = __builtin_bit_cast(unsigned, l0);
                PL1[xt][hm] = __builtin_bit_cast(unsigned, l1);
            }
        }

        // ---- stage B: A-frags are lane-local (W1 was stored k-permuted) ----
        // MFMA ks uses h(ks,kg,j) = ks*32 + (j>>2)*16 + kg*4 + (j&3):
        //   A-frag = [PH0[2ks], PH1[2ks], PH0[2ks+1], PH1[2ks+1]]
        f32x4 acc2[2][8];
#pragma unroll
        for (int xt = 0; xt < 2; ++xt)
#pragma unroll
            for (int nt = 0; nt < 8; ++nt) acc2[xt][nt] = (f32x4){0.f, 0.f, 0.f, 0.f};
#pragma unroll
        for (int ks = 0; ks < 4; ++ks) {
            f16x8 paH[2], paL[2];
#pragma unroll
            for (int xt = 0; xt < 2; ++xt) {
                u32x4 ph = {PH0[xt][2 * ks], PH1[xt][2 * ks],
                            PH0[xt][2 * ks + 1], PH1[xt][2 * ks + 1]};
                u32x4 pl = {PL0[xt][2 * ks], PL1[xt][2 * ks],
                            PL0[xt][2 * ks + 1], PL1[xt][2 * ks + 1]};
                paH[xt] = __builtin_bit_cast(f16x8, ph);
                paL[xt] = __builtin_bit_cast(f16x8, pl);
            }
#pragma unroll
            for (int nt = 0; nt < 8; ++nt) {
                f16x8 wf = *(const f16x8*)(w1s + ((nt * 4 + ks) * 64 + lane) * 8);
#pragma unroll
                for (int xt = 0; xt < 2; ++xt) {
                    acc2[xt][nt] = mfma16(paH[xt], wf, acc2[xt][nt]);
                    acc2[xt][nt] = mfma16(paL[xt], wf, acc2[xt][nt]);
                }
            }
        }

        // ---- epilogue B: relu(h2+b1).wmean, 16-lane reduce, store ----
        float ms[2][4];
#pragma unroll
        for (int xt = 0; xt < 2; ++xt)
#pragma unroll
            for (int r = 0; r < 4; ++r) ms[xt][r] = 0.f;
#pragma unroll
        for (int nt = 0; nt < 8; ++nt)
#pragma unroll
            for (int xt = 0; xt < 2; ++xt)
#pragma unroll
                for (int r = 0; r < 4; ++r) {
                    float v = acc2[xt][nt][r] + b1v[nt];
                    v = v > 0.f ? v : 0.f;
                    ms[xt][r] += v * wmv[nt];
                }
#pragma unroll
        for (int off = 1; off < 16; off <<= 1)
#pragma unroll
            for (int xt = 0; xt < 2; ++xt)
#pragma unroll
                for (int r = 0; r < 4; ++r)
                    ms[xt][r] += __shfl_xor(ms[xt][r], off, 64);
        if (lm == 0) {
#pragma unroll
            for (int xt = 0; xt < 2; ++xt) {
                f32x4 o = {ms[xt][0], ms[xt][1], ms[xt][2], ms[xt][3]};
                *(f32x4*)(m + (unsigned)u * BTOT + xbase + xt * 16 + kg * 4) = o;
            }
        }

        // ---- write prefetched Weff into other buffer, single barrier ----
        if (hasNext) {
            *(u32x4*)(wefs[cur ^ 1] + t * 8) = pf0;
            *(u32x4*)(wefs[cur ^ 1] + (512 + t) * 8) = pf1;
            __syncthreads();
            cur ^= 1;
        }
    }
}

__global__ void reduce_out(const float* __restrict__ m,
                           const int* __restrict__ ubyc,
                           const float* __restrict__ misc,
                           float* __restrict__ out) {
    int idx = blockIdx.x * 256 + threadIdx.x;   // bt*20 + a
    if (idx >= BTOT * NACT) return;
    int bt = idx / NACT, a = idx % NACT;
    float s = 0.f;
#pragma unroll
    for (int j = 0; j < 6; ++j) s += m[ubyc[a * 6 + j] * BTOT + bt];
    out[idx] = s * (1.f / 6.f) + misc[2 * HID];
}

extern "C" void kernel_launch(void* const* d_in, const int* in_sizes, int n_in,
                              void* d_out, int out_size, void* d_ws, size_t ws_size,
                              hipStream_t stream) {
    const float* x       = (const float*)d_in[0];
    const float* eqw     = (const float*)d_in[1];
    const float* eq_bias = (const float*)d_in[2];
    const float* W1      = (const float*)d_in[3];
    const float* b1      = (const float*)d_in[4];
    const float* Wout    = (const float*)d_in[5];
    const float* bout    = (const float*)d_in[6];
    float* out           = (float*)d_out;

    char* ws = (char*)d_ws;
    unsigned short* weff = (unsigned short*)(ws + WEFF_OFF);
    unsigned short* xhb  = (unsigned short*)(ws + XH_OFF);
    unsigned short* xlb  = (unsigned short*)(ws + XL_OFF);
    unsigned short* w1f  = (unsigned short*)(ws + W1F_OFF);
    float* misc   = (float*)(ws + MISC_OFF);
    int* cayley   = (int*)(ws + CAYL_OFF);
    int* fpt      = (int*)(ws + FPT_OFF);
    int* s4list   = (int*)(ws + S4_OFF);
    int* crep     = (int*)(ws + CREP_OFF);
    int* ubyc     = (int*)(ws + UBYC_OFF);
    float* Abuf   = (float*)(ws + ABUF_OFF);
    float* mbuf   = (float*)(ws + M_OFF);   // aliases Abuf (dead by mlp)

    hipLaunchKernelGGL(prep, dim3(609), dim3(256), 0, stream,
                       x, W1, eq_bias, Wout, bout,
                       cayley, fpt, s4list, crep, ubyc, misc, xhb, xlb, w1f);
    hipLaunchKernelGGL(weff_stage1, dim3(120, 4), dim3(256), 0, stream,
                       eqw, cayley, fpt, s4list, Abuf);
    hipLaunchKernelGGL(weff_stage2, dim3(120), dim3(256), 0, stream,
                       Abuf, cayley, fpt, crep, weff);
    hipLaunchKernelGGL(mlp_mfma, dim3(240), dim3(512), 0, stream,
                       xhb, xlb, weff, w1f, b1, misc, mbuf);
    hipLaunchKernelGGL(reduce_out, dim3((BTOT * NACT + 255) / 256), dim3(256), 0, stream,
                       mbuf, ubyc, misc, out);
}

// Round 10
// 60.456 us; speedup vs baseline: 2.2744x; 1.5556x over previous
//
#include <hip/hip_runtime.h>

typedef _Float16 f16;
typedef __attribute__((ext_vector_type(8))) _Float16 f16x8;
typedef __attribute__((ext_vector_type(4))) float f32x4;
typedef __attribute__((ext_vector_type(4))) unsigned int u32x4;
typedef __attribute__((ext_vector_type(8))) unsigned short ushort8;

#define QF   64
#define GG   120
#define HID  128
#define NACT 20
#define BTOT 2048
#define UCH  4

// ---- workspace layout (bytes) ----
#define WEFF_OFF 0u           // 120 * 16KB f16 frag-order = 1,966,080
#define XH_OFF   1966080u     // 2048*64 f16 = 262,144
#define XL_OFF   2228224u
#define W1F_OFF  2490368u     // 32KB f16 frag-order (k-permuted)
#define MISC_OFF 2523136u     // bmean[128], wmean[128], cb
#define CAYL_OFF 2525184u     // 120*120 i32
#define FPT_OFF  2582784u     // 120*64 i32
#define S4_OFF   2613504u     // 24 i32 (pad)
#define CREP_OFF 2613632u     // 5 i32 (pad)
#define UBYC_OFF 2613760u     // 20*6 i32 (pad)
#define ABUF_OFF 2614272u     // 120*64*128 f32 = 3,932,160
#define M_OFF    ABUF_OFF     // m[120][2048] aliases ABUF (dead by mlp)

template <typename T>
__device__ __forceinline__ void keepv(T& v) { asm volatile("" : "+v"(v)); }

// ---- packed-nibble permutation helpers (register-only, no scratch) ----
// perm p stored as unsigned: nibble k (bits 4k..4k+3) = p[k], k=0..4
__device__ __forceinline__ unsigned idx_to_packed(int i) {
    unsigned avail = 0x43210u, pp = 0u;
    const int fct[4] = {24, 6, 2, 1};
#pragma unroll
    for (int k = 0; k < 4; ++k) {
        int d = i / fct[k]; i -= d * fct[k];
        pp |= ((avail >> (4 * d)) & 0xFu) << (4 * k);
        unsigned mask = (1u << (4 * d)) - 1u;
        avail = (avail & mask) | ((avail >> 4) & ~mask);
    }
    pp |= (avail & 0xFu) << 16;
    return pp;
}

__device__ __forceinline__ int packed_to_idx(unsigned pp) {
    const int fct[4] = {24, 6, 2, 1};
    int idx = 0;
#pragma unroll
    for (int k = 0; k < 4; ++k) {
        unsigned pk = (pp >> (4 * k)) & 0xFu;
        int c = 0;
#pragma unroll
        for (int j = k + 1; j < 5; ++j)
            c += (int)(((pp >> (4 * j)) & 0xFu) < pk);
        idx += c * fct[k];
    }
    return idx;
}

__device__ __forceinline__ unsigned compose_packed(unsigned pa, unsigned pb) {
    unsigned pc = 0;
#pragma unroll
    for (int k = 0; k < 5; ++k) {
        unsigned bk = (pb >> (4 * k)) & 0xFu;
        pc |= ((pa >> (4 * bk)) & 0xFu) << (4 * k);
    }
    return pc;
}

__device__ __forceinline__ unsigned invert_packed(unsigned pp) {
    unsigned pi = 0;
#pragma unroll
    for (int k = 0; k < 5; ++k)
        pi |= (unsigned)k << (4 * ((pp >> (4 * k)) & 0xFu));
    return pi;
}

__device__ __forceinline__ unsigned short f2h(float f) {
    f16 h = (f16)f;
    return __builtin_bit_cast(unsigned short, h);
}
__device__ __forceinline__ float h2f(unsigned short u) {
    return (float)__builtin_bit_cast(f16, u);
}

// One fully-parallel prep kernel: tables + input splits + misc.
__global__ void prep(const float* __restrict__ x, const float* __restrict__ W1,
                     const float* __restrict__ eq_bias, const float* __restrict__ Wout,
                     const float* __restrict__ bout,
                     int* __restrict__ cayley, int* __restrict__ fpt,
                     int* __restrict__ s4list, int* __restrict__ crep,
                     int* __restrict__ ubyc, float* __restrict__ misc,
                     unsigned short* __restrict__ xh, unsigned short* __restrict__ xl,
                     unsigned short* __restrict__ w1f) {
    int b = blockIdx.x, t = threadIdx.x;
    if (b < 57) {                         // cayley[a][c] = idx(perm_a o perm_c)
        int idx = b * 256 + t;
        if (idx < GG * GG) {
            int a = idx / GG, c = idx % GG;
            unsigned pa = idx_to_packed(a), pc = idx_to_packed(c);
            cayley[idx] = packed_to_idx(compose_packed(pa, pc));
        }
    } else if (b < 87) {                  // fpt[v][r] (featperm)
        int idx = (b - 57) * 256 + t;     // < 7680
        int v = idx >> 6, r = idx & 63;
        unsigned ppi = invert_packed(idx_to_packed(v));
        int val = r & 32;
#pragma unroll
        for (int k = 0; k < 5; ++k) {
            int pik = (ppi >> (4 * k)) & 0xF;
            val |= ((r >> (4 - pik)) & 1) << (4 - k);
        }
        fpt[idx] = val;
    } else if (b < 95) {                  // W1 -> f16 B-frags, k-PERMUTED order
        int idx = (b - 87) * 256 + t;     // < 2048
        int fg = idx >> 6, lane = idx & 63;
        int nt = fg >> 2, ks = fg & 3;
        int n = nt * 16 + (lane & 15), kg = lane >> 4;
        ushort8 v;
#pragma unroll
        for (int j = 0; j < 8; ++j) {
            // h(ks,kg,j) = ks*32 + (j>>2)*16 + kg*4 + (j&3)  -- matches E-frag layout
            int h = ks * 32 + ((j >> 2) << 4) + (kg << 2) + (j & 3);
            v[j] = f2h(W1[h * HID + n]);
        }
        *(ushort8*)(w1f + idx * 8) = v;
    } else if (b < 607) {                 // split x -> f16 hi/lo
        int idx = (b - 95) * 256 + t;     // < 131072
        float f = x[idx];
        unsigned short h = f2h(f);
        xh[idx] = h;
        xl[idx] = f2h(f - h2f(h));
    } else if (b == 607) {                // misc
        if (t < HID) {
            float s = 0.f;
            for (int g = 0; g < GG; ++g) s += eq_bias[g * HID + t];
            misc[t] = s * (1.f / GG);
            float wv = 0.f;
            for (int n = 0; n < NACT; ++n) wv += Wout[t * NACT + n];
            misc[HID + t] = wv * (1.f / NACT);
            if (t == 0) {
                float c = 0.f;
                for (int n = 0; n < NACT; ++n) c += bout[n];
                misc[2 * HID] = c * (1.f / NACT);
            }
        }
    } else {                              // group tables (all register-only now)
        if (t < 24) {                     // S4 (perms fixing slot 4)
            unsigned avail = 0x3210u, pp = 0u;
            const int f3[3] = {6, 2, 1};
            int i = t;
#pragma unroll
            for (int k = 0; k < 3; ++k) {
                int d = i / f3[k]; i -= d * f3[k];
                pp |= ((avail >> (4 * d)) & 0xFu) << (4 * k);
                unsigned mask = (1u << (4 * d)) - 1u;
                avail = (avail & mask) | ((avail >> 4) & ~mask);
            }
            pp |= (avail & 0xFu) << 12;
            pp |= 4u << 16;
            s4list[t] = packed_to_idx(pp);
        }
        if (t < 5) {                      // transposition (t 4); t=4 -> identity
            unsigned pp = 0x43210u;
            pp &= ~(0xFu << (4 * t));
            pp &= ~(0xFu << 16);
            pp |= 4u << (4 * t);
            pp |= (unsigned)t << 16;
            crep[t] = packed_to_idx(pp);
        }
        if (t < NACT) {                   // coset membership lists
            int cnt = 0;
            for (int p = 0; p < GG; ++p) {
                unsigned pp = idx_to_packed(p);
                int p0 = pp & 0xF, p1 = (pp >> 4) & 0xF;
                int a = p0 * 4 + (p1 > p0 ? p1 - 1 : p1);
                if (a == t) ubyc[t * 6 + cnt++] = p;
            }
        }
    }
}

// Stage 1: A[y][r][h] = sum_{s in S4} eqw[cayley[s][y]][fpt[s][r]][h]
// grid (120 y, 8 r-groups) x 256 thr; lane owns float4 of h; 24 independent
// dwordx4 loads per thread, each wave-load = 2 contiguous 512B segments.
__global__ void weff_stage1(const float* __restrict__ eqw,
                            const int* __restrict__ cayley,
                            const int* __restrict__ fpt,
                            const int* __restrict__ s4list,
                            float* __restrict__ Abuf) {
    __shared__ int sg[24];
    __shared__ int sq[24][8];
    int y = blockIdx.x, rbase = blockIdx.y * 8, t = threadIdx.x;
    if (t < 24) sg[t] = cayley[s4list[t] * GG + y];
    if (t < 192) sq[t >> 3][t & 7] = fpt[s4list[t >> 3] * QF + rbase + (t & 7)];
    __syncthreads();
    int h4 = (t & 31) * 4, rslot = t >> 5;
    f32x4 acc = {0.f, 0.f, 0.f, 0.f};
#pragma unroll
    for (int si = 0; si < 24; ++si) {
        const float* src = eqw + ((unsigned)(sg[si] * QF + sq[si][rslot])) * HID + h4;
        f32x4 v = *(const f32x4*)src;
        acc.x += v.x; acc.y += v.y; acc.z += v.z; acc.w += v.w;
    }
    *(f32x4*)(Abuf + ((unsigned)(y * QF + rbase + rslot)) * HID + h4) = acc;
}

// Stage 2: Weff[u][q][h] = (1/G) sum_i A[cay[ci][u]][fpt[ci][q]][h]; emit f16 A-frags
// frag order per u: [hm(8)][ks(2)][lane(64)] x ushort8, value = Weff[q][h],
// q = ks*32 + (lane>>4)*8 + j, h = hm*16 + (lane&15)
__global__ void weff_stage2(const float* __restrict__ Abuf,
                            const int* __restrict__ cayley,
                            const int* __restrict__ fpt,
                            const int* __restrict__ crep,
                            unsigned short* __restrict__ weff) {
    __shared__ float Wacc[HID][QF + 1];   // [h][q], stride 65
    __shared__ int yv[5];
    __shared__ int rp[5][64];
    int u = blockIdx.x, t = threadIdx.x;
    if (t < 5) yv[t] = cayley[crep[t] * GG + u];
    for (int i = t; i < 5 * 64; i += 256)
        rp[i >> 6][i & 63] = fpt[crep[i >> 6] * QF + (i & 63)];
    __syncthreads();
    int h = t & 127, qg = t >> 7;
    for (int i = 0; i < 32; ++i) {
        int q = qg * 32 + i;
        float s = 0.f;
#pragma unroll
        for (int j = 0; j < 5; ++j)
            s += Abuf[(unsigned)(yv[j] * QF + rp[j][q]) * HID + h];
        Wacc[h][q] = s * (1.f / GG);
    }
    __syncthreads();
    for (int e = t; e < 1024; e += 256) {
        int fg = e >> 6, lane = e & 63;
        int hm = fg >> 1, ks = fg & 1;
        int hh = hm * 16 + (lane & 15), q0 = ks * 32 + (lane >> 4) * 8;
        ushort8 v;
#pragma unroll
        for (int j = 0; j < 8; ++j) v[j] = f2h(Wacc[hh][q0 + j]);
        *(ushort8*)(weff + (unsigned)(u * 16 + fg) * 64 * 8 + lane * 8) = v;
    }
}

__device__ __forceinline__ f32x4 mfma16(f16x8 a, f16x8 b, f32x4 c) {
    return __builtin_amdgcn_mfma_f32_16x16x32_f16(a, b, c, 0, 0, 0);
}

// Fused MLP: 240 blocks x 512 thr; 8 waves x 32 rows; W1 + Weff(dbuf) in LDS (64KB);
// swapped stage-A (E^T in regs); stage-B A-frags are lane-local (k-permuted W1).
__global__ __launch_bounds__(512, 1)
void mlp_mfma(const unsigned short* __restrict__ xh,
              const unsigned short* __restrict__ xl,
              const unsigned short* __restrict__ weff,
              const unsigned short* __restrict__ w1f,
              const float* __restrict__ b1,
              const float* __restrict__ misc,
              float* __restrict__ m) {
    __shared__ __align__(16) unsigned short w1s[16384];      // 32KB
    __shared__ __align__(16) unsigned short wefs[2][8192];   // 2x16KB

    int bid = blockIdx.x;
    int rowtile = bid & 7;            // 8 row tiles of 256
    int uc = bid >> 3;                // 30 u-chunks
    int u0 = uc * UCH;
    int rowbase = rowtile * 256;
    int t = threadIdx.x;
    int w = t >> 6, lane = t & 63;
    int lm = lane & 15, kg = lane >> 4;
    int xbase = rowbase + w * 32;

    // stage W1 + Weff[u0] into LDS
#pragma unroll
    for (int i = 0; i < 4; ++i)
        *(u32x4*)(w1s + (i * 512 + t) * 8) = *(const u32x4*)(w1f + (i * 512 + t) * 8);
#pragma unroll
    for (int i = 0; i < 2; ++i)
        *(u32x4*)(wefs[0] + (i * 512 + t) * 8) =
            *(const u32x4*)(weff + (unsigned)u0 * 8192 + (i * 512 + t) * 8);

    // pin X frags (B-operand of swapped stage A): [xt][ks][hi/lo]
    f16x8 xb[2][2][2];
#pragma unroll
    for (int xt = 0; xt < 2; ++xt)
#pragma unroll
        for (int ks = 0; ks < 2; ++ks) {
            int off = (xbase + xt * 16 + lm) * QF + ks * 32 + kg * 8;
            xb[xt][ks][0] = *(const f16x8*)(xh + off);
            xb[xt][ks][1] = *(const f16x8*)(xl + off);
            keepv(xb[xt][ks][0]); keepv(xb[xt][ks][1]);
        }
    // pin b1 / wmean per lane (n = nt*16+lm)
    float b1v[8], wmv[8];
#pragma unroll
    for (int nt = 0; nt < 8; ++nt) {
        b1v[nt] = b1[nt * 16 + lm];
        wmv[nt] = misc[HID + nt * 16 + lm];
        keepv(b1v[nt]); keepv(wmv[nt]);
    }
    __syncthreads();

    int cur = 0;

#pragma unroll 1
    for (int ui = 0; ui < UCH; ++ui) {
        int u = u0 + ui;
        bool hasNext = (ui + 1 < UCH);
        // prefetch next-u Weff into regs (write to LDS after compute)
        u32x4 pf0, pf1;
        if (hasNext) {
            const unsigned short* ws = weff + (unsigned)(u + 1) * 8192;
            pf0 = *(const u32x4*)(ws + t * 8);
            pf1 = *(const u32x4*)(ws + (512 + t) * 8);
        }

        // ---- stage A (swapped): acc[xt][hm] = E^T tile ----
        // lane holds E for x-row = xbase+xt*16+lm, h = hm*16 + kg*4 + r
        f32x4 acc[2][8];
#pragma unroll
        for (int xt = 0; xt < 2; ++xt)
#pragma unroll
            for (int hm = 0; hm < 8; ++hm) acc[xt][hm] = (f32x4){0.f, 0.f, 0.f, 0.f};
        const unsigned short* wb = wefs[cur];
#pragma unroll
        for (int hm = 0; hm < 8; ++hm)
#pragma unroll
            for (int ks = 0; ks < 2; ++ks) {
                f16x8 wf = *(const f16x8*)(wb + ((hm * 2 + ks) * 64 + lane) * 8);
#pragma unroll
                for (int xt = 0; xt < 2; ++xt) {
                    acc[xt][hm] = mfma16(wf, xb[xt][ks][0], acc[xt][hm]);
                    acc[xt][hm] = mfma16(wf, xb[xt][ks][1], acc[xt][hm]);
                }
            }

        // ---- epilogue A: +bmean, relu, f16 split, pack ----
        // PH0[hm] = f16(e[r0]),f16(e[r1]);  PH1[hm] = r2,r3;  PL* = residuals
        unsigned PH0[2][8], PH1[2][8], PL0[2][8], PL1[2][8];
#pragma unroll
        for (int hm = 0; hm < 8; ++hm) {
            f32x4 bmv = *(const f32x4*)(misc + hm * 16 + kg * 4);
#pragma unroll
            for (int xt = 0; xt < 2; ++xt) {
                float e0 = acc[xt][hm][0] + bmv[0]; e0 = e0 > 0.f ? e0 : 0.f;
                float e1 = acc[xt][hm][1] + bmv[1]; e1 = e1 > 0.f ? e1 : 0.f;
                float e2 = acc[xt][hm][2] + bmv[2]; e2 = e2 > 0.f ? e2 : 0.f;
                float e3 = acc[xt][hm][3] + bmv[3]; e3 = e3 > 0.f ? e3 : 0.f;
                auto h0 = __builtin_amdgcn_cvt_pkrtz(e0, e1);
                auto h1 = __builtin_amdgcn_cvt_pkrtz(e2, e3);
                auto l0 = __builtin_amdgcn_cvt_pkrtz(e0 - (float)h0[0], e1 - (float)h0[1]);
                auto l1 = __builtin_amdgcn_cvt_pkrtz(e2 - (float)h1[0], e3 - (float)h1[1]);
                PH0[xt][hm] = __builtin_bit_cast(unsigned, h0);
                PH1[xt][hm] = __builtin_bit_cast(unsigned, h1);
                PL0[xt][hm] = __builtin_bit_cast(unsigned, l0);
                PL1[xt][hm] = __builtin_bit_cast(unsigned, l1);
            }
        }

        // ---- stage B: A-frags are lane-local (W1 was stored k-permuted) ----
        // MFMA ks uses h(ks,kg,j) = ks*32 + (j>>2)*16 + kg*4 + (j&3):
        //   A-frag = [PH0[2ks], PH1[2ks], PH0[2ks+1], PH1[2ks+1]]
        f32x4 acc2[2][8];
#pragma unroll
        for (int xt = 0; xt < 2; ++xt)
#pragma unroll
            for (int nt = 0; nt < 8; ++nt) acc2[xt][nt] = (f32x4){0.f, 0.f, 0.f, 0.f};
#pragma unroll
        for (int ks = 0; ks < 4; ++ks) {
            f16x8 paH[2], paL[2];
#pragma unroll
            for (int xt = 0; xt < 2; ++xt) {
                u32x4 ph = {PH0[xt][2 * ks], PH1[xt][2 * ks],
                            PH0[xt][2 * ks + 1], PH1[xt][2 * ks + 1]};
                u32x4 pl = {PL0[xt][2 * ks], PL1[xt][2 * ks],
                            PL0[xt][2 * ks + 1], PL1[xt][2 * ks + 1]};
                paH[xt] = __builtin_bit_cast(f16x8, ph);
                paL[xt] = __builtin_bit_cast(f16x8, pl);
            }
#pragma unroll
            for (int nt = 0; nt < 8; ++nt) {
                f16x8 wf = *(const f16x8*)(w1s + ((nt * 4 + ks) * 64 + lane) * 8);
#pragma unroll
                for (int xt = 0; xt < 2; ++xt) {
                    acc2[xt][nt] = mfma16(paH[xt], wf, acc2[xt][nt]);
                    acc2[xt][nt] = mfma16(paL[xt], wf, acc2[xt][nt]);
                }
            }
        }

        // ---- epilogue B: relu(h2+b1).wmean, 16-lane reduce, store ----
        float ms[2][4];
#pragma unroll
        for (int xt = 0; xt < 2; ++xt)
#pragma unroll
            for (int r = 0; r < 4; ++r) ms[xt][r] = 0.f;
#pragma unroll
        for (int nt = 0; nt < 8; ++nt)
#pragma unroll
            for (int xt = 0; xt < 2; ++xt)
#pragma unroll
                for (int r = 0; r < 4; ++r) {
                    float v = acc2[xt][nt][r] + b1v[nt];
                    v = v > 0.f ? v : 0.f;
                    ms[xt][r] += v * wmv[nt];
                }
#pragma unroll
        for (int off = 1; off < 16; off <<= 1)
#pragma unroll
            for (int xt = 0; xt < 2; ++xt)
#pragma unroll
                for (int r = 0; r < 4; ++r)
                    ms[xt][r] += __shfl_xor(ms[xt][r], off, 64);
        if (lm == 0) {
#pragma unroll
            for (int xt = 0; xt < 2; ++xt) {
                f32x4 o = {ms[xt][0], ms[xt][1], ms[xt][2], ms[xt][3]};
                *(f32x4*)(m + (unsigned)u * BTOT + xbase + xt * 16 + kg * 4) = o;
            }
        }

        // ---- write prefetched Weff into other buffer, single barrier ----
        if (hasNext) {
            *(u32x4*)(wefs[cur ^ 1] + t * 8) = pf0;
            *(u32x4*)(wefs[cur ^ 1] + (512 + t) * 8) = pf1;
            __syncthreads();
            cur ^= 1;
        }
    }
}

__global__ void reduce_out(const float* __restrict__ m,
                           const int* __restrict__ ubyc,
                           const float* __restrict__ misc,
                           float* __restrict__ out) {
    int idx = blockIdx.x * 256 + threadIdx.x;   // bt*20 + a
    if (idx >= BTOT * NACT) return;
    int bt = idx / NACT, a = idx % NACT;
    float s = 0.f;
#pragma unroll
    for (int j = 0; j < 6; ++j) s += m[ubyc[a * 6 + j] * BTOT + bt];
    out[idx] = s * (1.f / 6.f) + misc[2 * HID];
}

extern "C" void kernel_launch(void* const* d_in, const int* in_sizes, int n_in,
                              void* d_out, int out_size, void* d_ws, size_t ws_size,
                              hipStream_t stream) {
    const float* x       = (const float*)d_in[0];
    const float* eqw     = (const float*)d_in[1];
    const float* eq_bias = (const float*)d_in[2];
    const float* W1      = (const float*)d_in[3];
    const float* b1      = (const float*)d_in[4];
    const float* Wout    = (const float*)d_in[5];
    const float* bout    = (const float*)d_in[6];
    float* out           = (float*)d_out;

    char* ws = (char*)d_ws;
    unsigned short* weff = (unsigned short*)(ws + WEFF_OFF);
    unsigned short* xhb  = (unsigned short*)(ws + XH_OFF);
    unsigned short* xlb  = (unsigned short*)(ws + XL_OFF);
    unsigned short* w1f  = (unsigned short*)(ws + W1F_OFF);
    float* misc   = (float*)(ws + MISC_OFF);
    int* cayley   = (int*)(ws + CAYL_OFF);
    int* fpt      = (int*)(ws + FPT_OFF);
    int* s4list   = (int*)(ws + S4_OFF);
    int* crep     = (int*)(ws + CREP_OFF);
    int* ubyc     = (int*)(ws + UBYC_OFF);
    float* Abuf   = (float*)(ws + ABUF_OFF);
    float* mbuf   = (float*)(ws + M_OFF);   // aliases Abuf (dead by mlp)

    hipLaunchKernelGGL(prep, dim3(609), dim3(256), 0, stream,
                       x, W1, eq_bias, Wout, bout,
                       cayley, fpt, s4list, crep, ubyc, misc, xhb, xlb, w1f);
    hipLaunchKernelGGL(weff_stage1, dim3(120, 8), dim3(256), 0, stream,
                       eqw, cayley, fpt, s4list, Abuf);
    hipLaunchKernelGGL(weff_stage2, dim3(120), dim3(256), 0, stream,
                       Abuf, cayley, fpt, crep, weff);
    hipLaunchKernelGGL(mlp_mfma, dim3(240), dim3(512), 0, stream,
                       xhb, xlb, weff, w1f, b1, misc, mbuf);
    hipLaunchKernelGGL(reduce_out, dim3((BTOT * NACT + 255) / 256), dim3(256), 0, stream,
                       mbuf, ubyc, misc, out);
}